// Round 4
// baseline (340.259 us; speedup 1.0000x reference)
//
#include <hip/hip_runtime.h>

typedef _Float16 f16;
typedef __attribute__((ext_vector_type(4))) _Float16 f16x4;
typedef __attribute__((ext_vector_type(8))) _Float16 f16x8;
typedef __attribute__((ext_vector_type(4))) float f32x4;

#define GLB_AS __attribute__((address_space(1)))
#define LDS_AS __attribute__((address_space(3)))

__device__ __forceinline__ void async_copy16(const void* g, void* l) {
  // 16B-per-lane global->LDS DMA; LDS dest = wave-uniform base + lane*16
  __builtin_amdgcn_global_load_lds((const GLB_AS void*)g, (LDS_AS void*)l, 16, 0, 0);
}

#define WAITVM(N) asm volatile("s_waitcnt vmcnt(" #N ")" ::: "memory")
#define BAR() __builtin_amdgcn_s_barrier()
#define SB0() __builtin_amdgcn_sched_barrier(0)

// Stage granule g_ (K-slice of 32) for A (IA insts) and B (2 insts).
// Source global chunk is pre-inverse-swizzled (rule 21): LDS stays linear,
// reads apply the same XOR. Each inst covers 128 rows (8 waves x 16).
#define STAGE(g_) do {                                                       \
    const long _k = (long)(g_) * 32;                                         \
    f16* _da = &Ash[(g_) & 3][w16 * 32];                                     \
    async_copy16(Ag + _k, _da);                                              \
    if constexpr (IA == 2) async_copy16(Ag + _k + 128l * lda, _da + 4096);   \
    f16* _db = &Bsh[(g_) & 3][w16 * 32];                                     \
    async_copy16(Bg + _k, _db);                                              \
    async_copy16(Bg + _k + 128l * ldb, _db + 4096);                          \
  } while (0)

// ---------------------------------------------------------------------------
// Minimal-sync counted-vmcnt GEMM: C[m][n] = sum_k A[m][k]*B[n][k]
// 512 threads = 8 waves (2M x 4N). Granule = K-slice of 32 (one MFMA depth),
// 4-deep circular LDS buffer. Per granule:
//   issue stage(g+3) -> plain-C++ fragment ds_reads -> MFMA cluster
//   -> counted WAITVM (keep 2 granules in flight; NEVER 0 mid-loop)
//   -> one s_barrier (+ SB0 hoist-guard only).
// Rationale (rounds 0-3 all ~640 TF): bank conflicts ruled out (measured-0
// swizzle, no effect); LDS/MFMA floors ~1400/1030 cyc/K-tile vs 4000 observed
// -> the residual was barrier count + lgkmcnt(0)/sched_barrier(0) pinning,
// which serialized {all reads} -> {all MFMAs} and defeated the compiler's
// fine lgkmcnt interleave (m97-verified). Here: 1 barrier per 32-of-K, no
// lgkm pinning, no setprio (m190: null in lockstep GEMM).
//
// LDS swizzle (round-2 formula, measured SQ_LDS_BANK_CONFLICT == 0):
// LDS chunk-pos p of row r holds global chunk p ^ ((r>>1)&3); staging
// realizes it by pre-swizzling the per-lane global source chunk; reads
// use chunk quad ^ ((r16>>1)&3).
//
// MODE 0 (projection): y-inner, (x,z)-outer -> XCD j owns row-slab y==j mod 8
// MODE 1 (attention):  z = (n%8)>>1 -> batch bound to an XCD pair
// ---------------------------------------------------------------------------
template <int BM, int BN, typename OutT, int MODE, bool BIAS>
__global__ __launch_bounds__(512, 2) void gemmc(
    const f16* __restrict__ A, const f16* __restrict__ B, OutT* __restrict__ C,
    int lda, int ldb, int ldc, int K, long sA, long sB, long sC,
    int tiles_x, int tiles_y,
    const float* __restrict__ b0, const float* __restrict__ b1,
    const float* __restrict__ b2)
{
  constexpr int WM = BM / 2, WN = BN / 4;     // per-wave output
  constexpr int RM = WM / 16, RN = WN / 16;   // frag repeats: (4,4) or (8,4)
  constexpr int IA = BM / 128;                // A stage insts per granule
  constexpr int IT = IA + 2;                  // insts per granule: 3 or 4
  static_assert(RN == 4 && BN == 256, "template assumes BN=256");

  __shared__ __align__(16) f16 Ash[4][BM * 32];
  __shared__ __align__(16) f16 Bsh[4][BN * 32];

  int bx, by, bz;
  {
    const int n = blockIdx.x;
    if (MODE == 0) {
      by = n % tiles_y;
      const int r = n / tiles_y;
      bx = r % tiles_x;
      bz = r / tiles_x;
    } else {
      const int j = n & 7, i = n >> 3, th = tiles_y >> 1;
      bz = j >> 1;
      bx = i / th;
      by = (j & 1) * th + i % th;
    }
  }

  A += (long)bz * sA;
  B += (long)bz * sB;
  C += (long)bz * sC;

  const int tid  = threadIdx.x;
  const int wave = tid >> 6, lane = tid & 63;
  const int wr = wave >> 2, wc = wave & 3;
  const int m0 = by * BM, n0 = bx * BN;
  const int r16 = lane & 15, quad = lane >> 4;
  const int w16 = wave * 16;

  // staging source: row = [inst*128 +] w16 + (lane>>2); chunk pre-swizzled
  const int cg8 = (((lane & 3) ^ ((lane >> 3) & 3)) * 8);
  const f16* Ag = A + (long)(m0 + w16 + (lane >> 2)) * lda + cg8;
  const f16* Bg = B + (long)(n0 + w16 + (lane >> 2)) * ldb + cg8;

  const int NG = K / 32;  // >= 32 for all shapes here

  // prologue: granules 0,1,2 in flight
  STAGE(0); STAGE(1); STAGE(2);

  f32x4 acc[RM][RN] = {};

  // fragment reads: row = w-base + frag*16 + r16, chunk = quad ^ ((r16>>1)&3)
  const int rc  = (quad ^ ((r16 >> 1) & 3)) * 8;
  const int rdA = (wr * WM + r16) * 32 + rc;
  const int rdB = (wc * WN + r16) * 32 + rc;

  if constexpr (IT == 3) { WAITVM(6); } else { WAITVM(8); }
  BAR(); SB0();

  for (int g = 0; g < NG; ++g) {
    if (g + 3 < NG) STAGE(g + 3);  // overwrites buf[(g-1)&3], fenced by BAR

    const f16* As = Ash[g & 3];
    const f16* Bs = Bsh[g & 3];
    f16x8 af[RM], bf[4];
#pragma unroll
    for (int j = 0; j < 4; j++) bf[j] = *(const f16x8*)&Bs[rdB + j * 512];
#pragma unroll
    for (int i = 0; i < RM; i++) af[i] = *(const f16x8*)&As[rdA + i * 512];
    // compiler inserts fine-grained lgkmcnt between reads and MFMAs; no pins
#pragma unroll
    for (int i = 0; i < RM; i++)
#pragma unroll
      for (int j = 0; j < 4; j++)
        acc[i][j] = __builtin_amdgcn_mfma_f32_16x16x32_f16(af[i], bf[j], acc[i][j], 0, 0, 0);

    if (g < NG - 1) {
      // granule g+1 must be landed; keep the rest in flight (never drain)
      if (g <= NG - 4) { if constexpr (IT == 3) { WAITVM(6); } else { WAITVM(8); } }
      else if (g == NG - 3) { if constexpr (IT == 3) { WAITVM(3); } else { WAITVM(4); } }
      else { WAITVM(0); }
      BAR(); SB0();
    }
  }

  // epilogue. C/D layout (verified m89): col = lane&15, row = (lane>>4)*4 + reg
  float bias_j[RN];
#pragma unroll
  for (int j = 0; j < RN; j++) bias_j[j] = 0.f;
  if constexpr (BIAS) {
    const float* bias = (bz == 0) ? b0 : (bz == 1) ? b1 : b2;
#pragma unroll
    for (int j = 0; j < RN; j++) bias_j[j] = bias[n0 + wc * WN + j * 16 + r16];
  }
#pragma unroll
  for (int i = 0; i < RM; i++)
#pragma unroll
    for (int j = 0; j < RN; j++)
#pragma unroll
      for (int r = 0; r < 4; r++) {
        long row = m0 + wr * WM + i * 16 + quad * 4 + r;
        long col = n0 + wc * WN + j * 16 + r16;
        C[row * (long)ldc + col] = (OutT)(acc[i][j][r] + bias_j[j]);
      }
}

// ---------------------------------------------------------------------------
// One launch casts x (8.39M) + Wq/Wk/Wv (1.05M each) fp32 -> fp16.
__global__ __launch_bounds__(256) void cast_all(
    const float* __restrict__ x, const float* __restrict__ Wq,
    const float* __restrict__ Wk, const float* __restrict__ Wv,
    f16* __restrict__ Xh, f16* __restrict__ Wh)
{
  const long off = (long)blockIdx.x * 1024 + threadIdx.x * 4;
  const float* src;
  f16* dst;
  if (off < 8388608L) {
    src = x + off;
    dst = Xh + off;
  } else {
    const long o = off - 8388608L;
    src = (o < 1048576L) ? Wq + o
        : (o < 2097152L) ? Wk + (o - 1048576L)
                         : Wv + (o - 2097152L);
    dst = Wh + o;
  }
  const float4 v = *(const float4*)src;
  f16x4 h;
  h.x = (f16)v.x; h.y = (f16)v.y; h.z = (f16)v.z; h.w = (f16)v.w;
  *(f16x4*)dst = h;
}

// LayerNorm (gamma/beta; bias already folded into GEMM epilogue).
// One block per row, in-place fp16. grid (8192, 3)
__global__ __launch_bounds__(256) void ln_kernel(
    f16* __restrict__ P, const float* __restrict__ gamma,
    const float* __restrict__ beta)
{
  f16* p = P + (long)blockIdx.y * 8388608 + (long)blockIdx.x * 1024;
  const int tid = threadIdx.x;
  const int e = tid * 4;

  f16x4 raw = *(const f16x4*)(p + e);
  float v0 = (float)raw.x, v1 = (float)raw.y;
  float v2 = (float)raw.z, v3 = (float)raw.w;
  float s  = v0 + v1 + v2 + v3;
  float s2 = v0 * v0 + v1 * v1 + v2 * v2 + v3 * v3;

#pragma unroll
  for (int off = 32; off > 0; off >>= 1) {
    s  += __shfl_down(s, off, 64);
    s2 += __shfl_down(s2, off, 64);
  }
  __shared__ float red[10];
  const int wave = tid >> 6, lane = tid & 63;
  if (lane == 0) { red[wave] = s; red[4 + wave] = s2; }
  __syncthreads();
  if (tid == 0) {
    red[8] = red[0] + red[1] + red[2] + red[3];
    red[9] = red[4] + red[5] + red[6] + red[7];
  }
  __syncthreads();
  const float mu   = red[8] * (1.f / 1024.f);
  const float var  = red[9] * (1.f / 1024.f) - mu * mu;
  const float rstd = rsqrtf(var + 1e-5f);

  float4 gg = *(const float4*)(gamma + e);
  float4 be = *(const float4*)(beta + e);
  f16x4 o;
  o.x = (f16)((v0 - mu) * rstd * gg.x + be.x);
  o.y = (f16)((v1 - mu) * rstd * gg.y + be.y);
  o.z = (f16)((v2 - mu) * rstd * gg.z + be.z);
  o.w = (f16)((v3 - mu) * rstd * gg.w + be.w);
  *(f16x4*)(p + e) = o;
}

// V (S x D, fp16) -> Vt (D x S, fp16), per batch. grid (D/64, S/64, B)
__global__ __launch_bounds__(256) void transpose_kernel(const f16* __restrict__ V,
                                                        f16* __restrict__ Vt)
{
  const int S = 2048, D = 1024;
  const f16* v = V + (long)blockIdx.z * ((long)S * D);
  f16* vt = Vt + (long)blockIdx.z * ((long)D * S);
  __shared__ f16 tile[64][66];  // +2 pad -> conflict-free transposed reads
  const int d0 = blockIdx.x * 64, j0 = blockIdx.y * 64;
  const int tx = threadIdx.x & 63, ty = threadIdx.x >> 6;
#pragma unroll
  for (int r = ty; r < 64; r += 4)
    tile[r][tx] = v[(long)(j0 + r) * D + d0 + tx];
  __syncthreads();
#pragma unroll
  for (int r = ty; r < 64; r += 4)
    vt[(long)(d0 + r) * S + j0 + tx] = tile[tx][r];
}

// Row softmax over 2048 fp32 logits; writes fp16 probs in-place (first half of row).
__global__ __launch_bounds__(256) void softmax_kernel(float* __restrict__ Sc)
{
  float* srow = Sc + (long)blockIdx.x * 2048;
  const int tid = threadIdx.x;
  float4 a = ((const float4*)srow)[tid];
  float4 b = ((const float4*)srow)[256 + tid];

  float m = fmaxf(fmaxf(fmaxf(a.x, a.y), fmaxf(a.z, a.w)),
                  fmaxf(fmaxf(b.x, b.y), fmaxf(b.z, b.w)));
#pragma unroll
  for (int off = 32; off > 0; off >>= 1) m = fmaxf(m, __shfl_down(m, off, 64));
  __shared__ float red[6];
  const int wave = tid >> 6, lane = tid & 63;
  if (lane == 0) red[wave] = m;
  __syncthreads();
  if (tid == 0) red[4] = fmaxf(fmaxf(red[0], red[1]), fmaxf(red[2], red[3]));
  __syncthreads();
  const float M = red[4];

  a.x = __expf(a.x - M); a.y = __expf(a.y - M);
  a.z = __expf(a.z - M); a.w = __expf(a.w - M);
  b.x = __expf(b.x - M); b.y = __expf(b.y - M);
  b.z = __expf(b.z - M); b.w = __expf(b.w - M);
  float s = a.x + a.y + a.z + a.w + b.x + b.y + b.z + b.w;
#pragma unroll
  for (int off = 32; off > 0; off >>= 1) s += __shfl_down(s, off, 64);
  if (lane == 0) red[wave] = s;
  __syncthreads();
  if (tid == 0) red[5] = red[0] + red[1] + red[2] + red[3];
  __syncthreads();
  const float inv = 1.0f / red[5];

  f16* orow = (f16*)srow;  // safe: all reads happened before first barrier
  f16x4 oa, ob;
  oa.x = (f16)(a.x * inv); oa.y = (f16)(a.y * inv);
  oa.z = (f16)(a.z * inv); oa.w = (f16)(a.w * inv);
  ob.x = (f16)(b.x * inv); ob.y = (f16)(b.y * inv);
  ob.z = (f16)(b.z * inv); ob.w = (f16)(b.w * inv);
  ((f16x4*)orow)[tid]       = oa;
  ((f16x4*)orow)[256 + tid] = ob;
}

// ---------------------------------------------------------------------------
extern "C" void kernel_launch(void* const* d_in, const int* in_sizes, int n_in,
                              void* d_out, int out_size, void* d_ws, size_t ws_size,
                              hipStream_t stream)
{
  const float* x     = (const float*)d_in[0];
  const float* Wq    = (const float*)d_in[1];
  const float* bq    = (const float*)d_in[2];
  const float* Wk    = (const float*)d_in[3];
  const float* bk    = (const float*)d_in[4];
  const float* Wv    = (const float*)d_in[5];
  const float* bv    = (const float*)d_in[6];
  const float* gamma = (const float*)d_in[7];
  const float* beta  = (const float*)d_in[8];
  float* out = (float*)d_out;

  // ws layout (needs 128 MB):
  //  [0,48)MB   P  : Q,K,V fp16 slabs (8192x1024 each), LN in-place
  //  [48,64)MB  Vt : V transposed per batch (1024x2048 fp16)
  //  [64,128)MB Sc : scores fp32 (4 x 2048x2048); softmax writes fp16 probs in-place
  //  Xh/Wh aliased inside the Sc region (dead before scores are written)
  char* ws = (char*)d_ws;
  f16*   P  = (f16*)(ws);
  f16*   Vt = (f16*)(ws + (48u << 20));
  float* Sc = (float*)(ws + (64u << 20));
  f16*   Xh = (f16*)(ws + (64u << 20));
  f16*   Wh = (f16*)(ws + (80u << 20));

  // 1. fp32 -> fp16 casts (single launch)
  cast_all<<<11264, 256, 0, stream>>>(x, Wq, Wk, Wv, Xh, Wh);

  // 2. projections + bias: P_h = Xh · Wh^T + b_h  (M=8192, N=1024, K=1024, z=h)
  //    BM=128, BN=256 -> 64 x 4 x 3 = 768 blocks (3/CU exact)
  gemmc<128, 256, f16, 0, true><<<768, 512, 0, stream>>>(
      Xh, Wh, P, 1024, 1024, 1024, 1024, 0L, 1048576L, 8388608L,
      4, 64, bq, bk, bv);

  // 3. LayerNorm (gamma/beta), in-place fp16
  ln_kernel<<<dim3(8192, 3), 256, 0, stream>>>(P, gamma, beta);

  // 4. V -> Vt per batch
  transpose_kernel<<<dim3(16, 32, 4), 256, 0, stream>>>(P + 2L * 8388608, Vt);

  // 5. scores: Sc_b = Q_b · K_b^T  (M=N=2048, K=1024, z=batch, fp32 out)
  //    BM=BN=256 -> 8 x 8 x 4 = 256 blocks (1/CU exact)
  gemmc<256, 256, float, 1, false><<<256, 512, 0, stream>>>(
      P, P + 8388608, Sc, 1024, 1024, 2048, 1024, 2097152L, 2097152L, 4194304L,
      8, 8, nullptr, nullptr, nullptr);

  // 6. softmax rows (8192 rows), fp16 probs in-place (row pitch 4096 halves)
  softmax_kernel<<<8192, 256, 0, stream>>>(Sc);

  // 7. out_b = Pr_b · Vt_b^T  (M=2048, N=1024, K=2048, z=batch, fp32 out)
  //    BM=128, BN=256 -> 16 x 4 x 4 = 256 blocks (1/CU exact)
  gemmc<128, 256, float, 1, false><<<256, 512, 0, stream>>>(
      (const f16*)Sc, Vt, out, 4096, 2048, 1024, 2048, 8388608L, 2097152L, 2097152L,
      4, 16, nullptr, nullptr, nullptr);
}

// Round 5
// 308.826 us; speedup vs baseline: 1.1018x; 1.1018x over previous
//
#include <hip/hip_runtime.h>

typedef _Float16 f16;
typedef __attribute__((ext_vector_type(4))) _Float16 f16x4;
typedef __attribute__((ext_vector_type(8))) _Float16 f16x8;
typedef __attribute__((ext_vector_type(4))) float f32x4;

#define GLB_AS __attribute__((address_space(1)))
#define LDS_AS __attribute__((address_space(3)))

__device__ __forceinline__ void async_copy16(const void* g, void* l) {
  // 16B-per-lane global->LDS DMA; LDS dest = wave-uniform base + lane*16
  __builtin_amdgcn_global_load_lds((const GLB_AS void*)g, (LDS_AS void*)l, 16, 0, 0);
}

// ---------------------------------------------------------------------------
// Generic fp16 GEMM: C[m][n] = sum_k A[m*lda+k] * B[n*ldb+k]   (both K-contig)
// BM=BN=128, BK=32, 256 threads (4 waves, 2x2), each wave 64x64 via 4x4 MFMA.
// Double-buffered LDS, ONE barrier per K-step (prefetch issued right after
// the barrier, lands during the MFMA body of the NEXT iteration).
//
// ROUND 5: occupancy attack. The structure is latency-bound (per-granule
// chain ~2200 cyc, hidden only by cross-block wave overlap, m114). r1 sat at
// 76 arch VGPR + 64 AGPR = 140 > 128 -> HW register quantum rounds to 256
// -> 2 waves/SIMD (25% occ, measured 29%). Fix: stream the A fragment
// (one af live instead of af[4]) and pin with __launch_bounds__(256,4)
// so total (unified VGPR+AGPR file) fits 128 -> 4 waves/SIMD.
//
// LDS chunk swizzle: verified-zero-conflict pair from round 3 (gemmc):
//   stage global chunk = (l&3) ^ ((l>>3)&3)   [LDS dest stays linear]
//   read  chunk        = quad ^ ((r16>>1)&3)
// (rule 21: both-sides-or-neither with global_load_lds.)
//
// 1D grid with explicit tile decode for XCD-aware L2 locality (XCD = n%8):
//  MODE 0 (projection): y-inner, (x,z)-outer -> XCD j owns row-slab y==j mod 8
//  MODE 1 (attention, ty=16, tz=4): z = (n%8)>>1 -> batch bound to an XCD pair
// ---------------------------------------------------------------------------
template <typename OutT, int MODE, bool BIAS>
__global__ __launch_bounds__(256, 4) void gemm_kn(
    const f16* __restrict__ A, const f16* __restrict__ B, OutT* __restrict__ C,
    int lda, int ldb, int ldc, int K, long sA, long sB, long sC,
    int tiles_x, int tiles_y,
    const float* __restrict__ b0, const float* __restrict__ b1,
    const float* __restrict__ b2)
{
  constexpr int BM = 128, BK = 32;
  __shared__ __align__(16) f16 Ash[2][BM * BK];
  __shared__ __align__(16) f16 Bsh[2][BM * BK];

  int bx, by, bz;
  {
    const int n = blockIdx.x;
    if (MODE == 0) {
      by = n % tiles_y;
      const int r = n / tiles_y;
      bx = r % tiles_x;
      bz = r / tiles_x;
    } else {
      const int j = n & 7, i = n >> 3;
      bz = j >> 1;                     // batch <- XCD pair
      bx = i >> 3;                     // x-outer: B-tile resident per step
      by = (j & 1) * 8 + (i & 7);      // y-inner within this XCD's half
    }
  }

  A += (long)bz * sA;
  B += (long)bz * sB;
  C += (long)bz * sC;

  const int tid  = threadIdx.x;
  const int wave = tid >> 6, lane = tid & 63;
  const int m0 = by * BM, n0 = bx * BM;
  const int wm = (wave >> 1) * 64, wn = (wave & 1) * 64;
  const int r16 = lane & 15, quad = lane >> 4;

  // staging: each wave fills rows [wave*32, wave*32+32) of both tiles,
  // 2 chunks of 16 rows; lane l -> row +(l>>2); global k-chunk pre-swizzled:
  // ((l&3) ^ ((l>>3)&3)) * 8 halves (16B). LDS dest stays linear.
  const int srow = wave * 32 + (lane >> 2);
  const int skb  = ((lane & 3) ^ ((lane >> 3) & 3)) * 8;
  const f16* Ag = A + (long)(m0 + srow) * lda + skb;
  const f16* Bg = B + (long)(n0 + srow) * ldb + skb;
  const int lo0 = (wave * 32) * BK;        // LDS row offset, 16-row chunk 0
  const int lo1 = (wave * 32 + 16) * BK;   // chunk 1

  // prologue: fill buffer 0
  async_copy16(Ag,                  &Ash[0][lo0]);
  async_copy16(Ag + 16 * (long)lda, &Ash[0][lo1]);
  async_copy16(Bg,                  &Bsh[0][lo0]);
  async_copy16(Bg + 16 * (long)ldb, &Bsh[0][lo1]);

  f32x4 acc[4][4] = {};

  // fragment-read chunk: matches staging swizzle, invariant per lane
  const int cchunk = (quad ^ ((r16 >> 1) & 3)) * 8;

  int buf = 0;
  for (int k0 = 0; k0 < K; k0 += BK, buf ^= 1) {
    __syncthreads();  // vmcnt(0): prefetch landed; all waves done with buf^1

    if (k0 + BK < K) {
      const int nb = buf ^ 1;
      const long k1 = k0 + BK;
      async_copy16(Ag + k1,                  &Ash[nb][lo0]);
      async_copy16(Ag + k1 + 16 * (long)lda, &Ash[nb][lo1]);
      async_copy16(Bg + k1,                  &Bsh[nb][lo0]);
      async_copy16(Bg + k1 + 16 * (long)ldb, &Bsh[nb][lo1]);
    }

    // register diet: keep bf[4] (16 VGPR) resident, stream af one at a time
    f16x8 bf[4];
#pragma unroll
    for (int j = 0; j < 4; j++)
      bf[j] = *(const f16x8*)&Bsh[buf][(wn + j * 16 + r16) * BK + cchunk];
#pragma unroll
    for (int i = 0; i < 4; i++) {
      f16x8 af = *(const f16x8*)&Ash[buf][(wm + i * 16 + r16) * BK + cchunk];
#pragma unroll
      for (int j = 0; j < 4; j++)
        acc[i][j] = __builtin_amdgcn_mfma_f32_16x16x32_f16(af, bf[j], acc[i][j], 0, 0, 0);
    }
  }

  // C/D layout (verified m89): col = lane&15, row = (lane>>4)*4 + reg
  float bias_j[4] = {0.f, 0.f, 0.f, 0.f};
  if (BIAS) {
    const float* bias = (bz == 0) ? b0 : (bz == 1) ? b1 : b2;
#pragma unroll
    for (int j = 0; j < 4; j++) bias_j[j] = bias[n0 + wn + j * 16 + r16];
  }
#pragma unroll
  for (int i = 0; i < 4; i++)
#pragma unroll
    for (int j = 0; j < 4; j++)
#pragma unroll
      for (int r = 0; r < 4; r++) {
        long row = m0 + wm + i * 16 + quad * 4 + r;
        long col = n0 + wn + j * 16 + r16;
        C[row * (long)ldc + col] = (OutT)(acc[i][j][r] + bias_j[j]);
      }
}

// ---------------------------------------------------------------------------
// One launch casts x (8.39M) + Wq/Wk/Wv (1.05M each) fp32 -> fp16.
__global__ __launch_bounds__(256) void cast_all(
    const float* __restrict__ x, const float* __restrict__ Wq,
    const float* __restrict__ Wk, const float* __restrict__ Wv,
    f16* __restrict__ Xh, f16* __restrict__ Wh)
{
  const long off = (long)blockIdx.x * 1024 + threadIdx.x * 4;
  const float* src;
  f16* dst;
  if (off < 8388608L) {
    src = x + off;
    dst = Xh + off;
  } else {
    const long o = off - 8388608L;
    src = (o < 1048576L) ? Wq + o
        : (o < 2097152L) ? Wk + (o - 1048576L)
                         : Wv + (o - 2097152L);
    dst = Wh + o;
  }
  const float4 v = *(const float4*)src;
  f16x4 h;
  h.x = (f16)v.x; h.y = (f16)v.y; h.z = (f16)v.z; h.w = (f16)v.w;
  *(f16x4*)dst = h;
}

// LayerNorm (gamma/beta; bias already folded into GEMM epilogue).
// One block per row, in-place fp16. grid (8192, 3)
__global__ __launch_bounds__(256) void ln_kernel(
    f16* __restrict__ P, const float* __restrict__ gamma,
    const float* __restrict__ beta)
{
  f16* p = P + (long)blockIdx.y * 8388608 + (long)blockIdx.x * 1024;
  const int tid = threadIdx.x;
  const int e = tid * 4;

  f16x4 raw = *(const f16x4*)(p + e);
  float v0 = (float)raw.x, v1 = (float)raw.y;
  float v2 = (float)raw.z, v3 = (float)raw.w;
  float s  = v0 + v1 + v2 + v3;
  float s2 = v0 * v0 + v1 * v1 + v2 * v2 + v3 * v3;

#pragma unroll
  for (int off = 32; off > 0; off >>= 1) {
    s  += __shfl_down(s, off, 64);
    s2 += __shfl_down(s2, off, 64);
  }
  __shared__ float red[10];
  const int wave = tid >> 6, lane = tid & 63;
  if (lane == 0) { red[wave] = s; red[4 + wave] = s2; }
  __syncthreads();
  if (tid == 0) {
    red[8] = red[0] + red[1] + red[2] + red[3];
    red[9] = red[4] + red[5] + red[6] + red[7];
  }
  __syncthreads();
  const float mu   = red[8] * (1.f / 1024.f);
  const float var  = red[9] * (1.f / 1024.f) - mu * mu;
  const float rstd = rsqrtf(var + 1e-5f);

  float4 gg = *(const float4*)(gamma + e);
  float4 be = *(const float4*)(beta + e);
  f16x4 o;
  o.x = (f16)((v0 - mu) * rstd * gg.x + be.x);
  o.y = (f16)((v1 - mu) * rstd * gg.y + be.y);
  o.z = (f16)((v2 - mu) * rstd * gg.z + be.z);
  o.w = (f16)((v3 - mu) * rstd * gg.w + be.w);
  *(f16x4*)(p + e) = o;
}

// V (S x D, fp16) -> Vt (D x S, fp16), per batch. grid (D/64, S/64, B)
__global__ __launch_bounds__(256) void transpose_kernel(const f16* __restrict__ V,
                                                        f16* __restrict__ Vt)
{
  const int S = 2048, D = 1024;
  const f16* v = V + (long)blockIdx.z * ((long)S * D);
  f16* vt = Vt + (long)blockIdx.z * ((long)D * S);
  __shared__ f16 tile[64][66];  // +2 pad -> conflict-free transposed reads
  const int d0 = blockIdx.x * 64, j0 = blockIdx.y * 64;
  const int tx = threadIdx.x & 63, ty = threadIdx.x >> 6;
#pragma unroll
  for (int r = ty; r < 64; r += 4)
    tile[r][tx] = v[(long)(j0 + r) * D + d0 + tx];
  __syncthreads();
#pragma unroll
  for (int r = ty; r < 64; r += 4)
    vt[(long)(d0 + r) * S + j0 + tx] = tile[tx][r];
}

// Row softmax over 2048 fp32 logits; writes fp16 probs in-place (first half of row).
__global__ __launch_bounds__(256) void softmax_kernel(float* __restrict__ Sc)
{
  float* srow = Sc + (long)blockIdx.x * 2048;
  const int tid = threadIdx.x;
  float4 a = ((const float4*)srow)[tid];
  float4 b = ((const float4*)srow)[256 + tid];

  float m = fmaxf(fmaxf(fmaxf(a.x, a.y), fmaxf(a.z, a.w)),
                  fmaxf(fmaxf(b.x, b.y), fmaxf(b.z, b.w)));
#pragma unroll
  for (int off = 32; off > 0; off >>= 1) m = fmaxf(m, __shfl_down(m, off, 64));
  __shared__ float red[6];
  const int wave = tid >> 6, lane = tid & 63;
  if (lane == 0) red[wave] = m;
  __syncthreads();
  if (tid == 0) red[4] = fmaxf(fmaxf(red[0], red[1]), fmaxf(red[2], red[3]));
  __syncthreads();
  const float M = red[4];

  a.x = __expf(a.x - M); a.y = __expf(a.y - M);
  a.z = __expf(a.z - M); a.w = __expf(a.w - M);
  b.x = __expf(b.x - M); b.y = __expf(b.y - M);
  b.z = __expf(b.z - M); b.w = __expf(b.w - M);
  float s = a.x + a.y + a.z + a.w + b.x + b.y + b.z + b.w;
#pragma unroll
  for (int off = 32; off > 0; off >>= 1) s += __shfl_down(s, off, 64);
  if (lane == 0) red[wave] = s;
  __syncthreads();
  if (tid == 0) red[5] = red[0] + red[1] + red[2] + red[3];
  __syncthreads();
  const float inv = 1.0f / red[5];

  f16* orow = (f16*)srow;  // safe: all reads happened before first barrier
  f16x4 oa, ob;
  oa.x = (f16)(a.x * inv); oa.y = (f16)(a.y * inv);
  oa.z = (f16)(a.z * inv); oa.w = (f16)(a.w * inv);
  ob.x = (f16)(b.x * inv); ob.y = (f16)(b.y * inv);
  ob.z = (f16)(b.z * inv); ob.w = (f16)(b.w * inv);
  ((f16x4*)orow)[tid]       = oa;
  ((f16x4*)orow)[256 + tid] = ob;
}

// ---------------------------------------------------------------------------
extern "C" void kernel_launch(void* const* d_in, const int* in_sizes, int n_in,
                              void* d_out, int out_size, void* d_ws, size_t ws_size,
                              hipStream_t stream)
{
  const float* x     = (const float*)d_in[0];
  const float* Wq    = (const float*)d_in[1];
  const float* bq    = (const float*)d_in[2];
  const float* Wk    = (const float*)d_in[3];
  const float* bk    = (const float*)d_in[4];
  const float* Wv    = (const float*)d_in[5];
  const float* bv    = (const float*)d_in[6];
  const float* gamma = (const float*)d_in[7];
  const float* beta  = (const float*)d_in[8];
  float* out = (float*)d_out;

  // ws layout (needs 128 MB):
  //  [0,48)MB   P  : Q,K,V fp16 slabs (8192x1024 each), LN in-place
  //  [48,64)MB  Vt : V transposed per batch (1024x2048 fp16)
  //  [64,128)MB Sc : scores fp32 (4 x 2048x2048); softmax writes fp16 probs in-place
  //  Xh/Wh aliased inside the Sc region (dead before scores are written)
  char* ws = (char*)d_ws;
  f16*   P  = (f16*)(ws);
  f16*   Vt = (f16*)(ws + (48u << 20));
  float* Sc = (float*)(ws + (64u << 20));
  f16*   Xh = (f16*)(ws + (64u << 20));
  f16*   Wh = (f16*)(ws + (80u << 20));

  // 1. fp32 -> fp16 casts (single launch)
  cast_all<<<11264, 256, 0, stream>>>(x, Wq, Wk, Wv, Xh, Wh);

  // 2. projections + bias: P_h = Xh · Wh^T + b_h  (M=8192, N=1024, K=1024, z=h)
  gemm_kn<f16, 0, true><<<1536, 256, 0, stream>>>(
      Xh, Wh, P, 1024, 1024, 1024, 1024, 0L, 1048576L, 8388608L,
      8, 64, bq, bk, bv);

  // 3. LayerNorm (gamma/beta), in-place fp16
  ln_kernel<<<dim3(8192, 3), 256, 0, stream>>>(P, gamma, beta);

  // 4. V -> Vt per batch
  transpose_kernel<<<dim3(16, 32, 4), 256, 0, stream>>>(P + 2L * 8388608, Vt);

  // 5. scores: Sc_b = Q_b · K_b^T  (M=N=2048, K=1024, z=batch, fp32 out)
  gemm_kn<float, 1, false><<<1024, 256, 0, stream>>>(
      P, P + 8388608, Sc, 1024, 1024, 2048, 1024, 2097152L, 2097152L, 4194304L,
      16, 16, nullptr, nullptr, nullptr);

  // 6. softmax rows (8192 rows), fp16 probs in-place (row pitch 4096 halves)
  softmax_kernel<<<8192, 256, 0, stream>>>(Sc);

  // 7. out_b = Pr_b · Vt_b^T  (M=2048, N=1024, K=2048, z=batch, fp32 out)
  gemm_kn<float, 1, false><<<512, 256, 0, stream>>>(
      (const f16*)Sc, Vt, out, 4096, 2048, 1024, 2048, 8388608L, 2097152L, 2097152L,
      8, 16, nullptr, nullptr, nullptr);
}

// Round 8
// 300.723 us; speedup vs baseline: 1.1315x; 1.0269x over previous
//
#include <hip/hip_runtime.h>

typedef _Float16 f16;
typedef __attribute__((ext_vector_type(4))) _Float16 f16x4;
typedef __attribute__((ext_vector_type(8))) _Float16 f16x8;
typedef __attribute__((ext_vector_type(4))) float f32x4;

#define GLB_AS __attribute__((address_space(1)))
#define LDS_AS __attribute__((address_space(3)))

__device__ __forceinline__ void async_copy16(const void* g, void* l) {
  // 16B-per-lane global->LDS DMA; LDS dest = wave-uniform base + lane*16
  __builtin_amdgcn_global_load_lds((const GLB_AS void*)g, (LDS_AS void*)l, 16, 0, 0);
}

#define WAITVM(N) asm volatile("s_waitcnt vmcnt(" #N ")" ::: "memory")
#define WAITLGKM0() asm volatile("s_waitcnt lgkmcnt(0)" ::: "memory")
#define BAR() __builtin_amdgcn_s_barrier()
#define SB0() __builtin_amdgcn_sched_barrier(0)

// ===========================================================================
// PROJECTION GEMM — r5 verbatim (best-measured: 72.8 us, VGPR 56, 0 conflicts)
// BM=BN=128, BK=32, 256 threads (4 waves 2x2), __syncthreads-paced dbuf.
// ===========================================================================
template <typename OutT, int MODE, bool BIAS>
__global__ __launch_bounds__(256, 4) void gemm_kn(
    const f16* __restrict__ A, const f16* __restrict__ B, OutT* __restrict__ C,
    int lda, int ldb, int ldc, int K, long sA, long sB, long sC,
    int tiles_x, int tiles_y,
    const float* __restrict__ b0, const float* __restrict__ b1,
    const float* __restrict__ b2)
{
  constexpr int BM = 128, BK = 32;
  __shared__ __align__(16) f16 Ash[2][BM * BK];
  __shared__ __align__(16) f16 Bsh[2][BM * BK];

  int bx, by, bz;
  {
    const int n = blockIdx.x;
    if (MODE == 0) {
      by = n % tiles_y;
      const int r = n / tiles_y;
      bx = r % tiles_x;
      bz = r / tiles_x;
    } else {
      const int j = n & 7, i = n >> 3;
      bz = j >> 1;
      bx = i >> 3;
      by = (j & 1) * 8 + (i & 7);
    }
  }

  A += (long)bz * sA;
  B += (long)bz * sB;
  C += (long)bz * sC;

  const int tid  = threadIdx.x;
  const int wave = tid >> 6, lane = tid & 63;
  const int m0 = by * BM, n0 = bx * BM;
  const int wm = (wave >> 1) * 64, wn = (wave & 1) * 64;
  const int r16 = lane & 15, quad = lane >> 4;

  // staging: wave fills rows [wave*32,+32); lane l -> row +(l>>2); global
  // k-chunk pre-swizzled ((l&3)^((l>>3)&3))*8 halves; LDS dest linear.
  const int srow = wave * 32 + (lane >> 2);
  const int skb  = ((lane & 3) ^ ((lane >> 3) & 3)) * 8;
  const f16* Ag = A + (long)(m0 + srow) * lda + skb;
  const f16* Bg = B + (long)(n0 + srow) * ldb + skb;
  const int lo0 = (wave * 32) * BK;
  const int lo1 = (wave * 32 + 16) * BK;

  async_copy16(Ag,                  &Ash[0][lo0]);
  async_copy16(Ag + 16 * (long)lda, &Ash[0][lo1]);
  async_copy16(Bg,                  &Bsh[0][lo0]);
  async_copy16(Bg + 16 * (long)ldb, &Bsh[0][lo1]);

  f32x4 acc[4][4] = {};

  const int cchunk = (quad ^ ((r16 >> 1) & 3)) * 8;

  int buf = 0;
  for (int k0 = 0; k0 < K; k0 += BK, buf ^= 1) {
    __syncthreads();  // vmcnt(0): prefetch landed; all waves done with buf^1

    if (k0 + BK < K) {
      const int nb = buf ^ 1;
      const long k1 = k0 + BK;
      async_copy16(Ag + k1,                  &Ash[nb][lo0]);
      async_copy16(Ag + k1 + 16 * (long)lda, &Ash[nb][lo1]);
      async_copy16(Bg + k1,                  &Bsh[nb][lo0]);
      async_copy16(Bg + k1 + 16 * (long)ldb, &Bsh[nb][lo1]);
    }

    // register diet: keep bf[4] resident, stream af one at a time
    f16x8 bf[4];
#pragma unroll
    for (int j = 0; j < 4; j++)
      bf[j] = *(const f16x8*)&Bsh[buf][(wn + j * 16 + r16) * BK + cchunk];
#pragma unroll
    for (int i = 0; i < 4; i++) {
      f16x8 af = *(const f16x8*)&Ash[buf][(wm + i * 16 + r16) * BK + cchunk];
#pragma unroll
      for (int j = 0; j < 4; j++)
        acc[i][j] = __builtin_amdgcn_mfma_f32_16x16x32_f16(af, bf[j], acc[i][j], 0, 0, 0);
    }
  }

  // C/D layout (verified m89): col = lane&15, row = (lane>>4)*4 + reg
  float bias_j[4] = {0.f, 0.f, 0.f, 0.f};
  if (BIAS) {
    const float* bias = (bz == 0) ? b0 : (bz == 1) ? b1 : b2;
#pragma unroll
    for (int j = 0; j < 4; j++) bias_j[j] = bias[n0 + wn + j * 16 + r16];
  }
#pragma unroll
  for (int i = 0; i < 4; i++)
#pragma unroll
    for (int j = 0; j < 4; j++)
#pragma unroll
      for (int r = 0; r < 4; r++) {
        long row = m0 + wm + i * 16 + quad * 4 + r;
        long col = n0 + wn + j * 16 + r16;
        C[row * (long)ldc + col] = (OutT)(acc[i][j][r] + bias_j[j]);
      }
}

// ===========================================================================
// ATTENTION GEMMs — r3 verbatim (best-measured scores/PV; part of 300.2 run)
// 512 threads = 8 waves (2M x 4N), BK=64 staged as two K-halves, phase-split
// with counted vmcnt (never 0 mid-loop).
// ===========================================================================
#define STAGE_A(t_, kk_) do {                                                \
    const long _k = (long)(t_) * 64 + (kk_) * 32;                            \
    f16* _d = &Ash[(t_) & 1][kk_][w16 * 32];                                 \
    async_copy16(Ag + _k, _d);                                               \
    if constexpr (IA == 2) async_copy16(Ag + _k + 128l * lda, _d + 4096);    \
  } while (0)
#define STAGE_B(t_, kk_) do {                                                \
    const long _k = (long)(t_) * 64 + (kk_) * 32;                            \
    f16* _d = &Bsh[(t_) & 1][kk_][w16 * 32];                                 \
    async_copy16(Bg + _k, _d);                                               \
    async_copy16(Bg + _k + 128l * ldb, _d + 4096);                           \
  } while (0)

template <int BM, int BN, typename OutT, int MODE, bool BIAS>
__global__ __launch_bounds__(512, 2) void gemm8p(
    const f16* __restrict__ A, const f16* __restrict__ B, OutT* __restrict__ C,
    int lda, int ldb, int ldc, int K, long sA, long sB, long sC,
    int tiles_x, int tiles_y,
    const float* __restrict__ b0, const float* __restrict__ b1,
    const float* __restrict__ b2)
{
  constexpr int WM = BM / 2, WN = BN / 4;
  constexpr int RM = WM / 16, RN = WN / 16;
  constexpr int IA = BM / 128;
  static_assert(RN == 4 && BN == 256, "template assumes BN=256");

  __shared__ __align__(16) f16 Ash[2][2][BM * 32];
  __shared__ __align__(16) f16 Bsh[2][2][BN * 32];

  int bx, by, bz;
  {
    const int n = blockIdx.x;
    if (MODE == 0) {
      by = n % tiles_y;
      const int r = n / tiles_y;
      bx = r % tiles_x;
      bz = r / tiles_x;
    } else {
      const int j = n & 7, i = n >> 3, th = tiles_y >> 1;
      bz = j >> 1;
      bx = i / th;
      by = (j & 1) * th + i % th;
    }
  }

  A += (long)bz * sA;
  B += (long)bz * sB;
  C += (long)bz * sC;

  const int tid  = threadIdx.x;
  const int wave = tid >> 6, lane = tid & 63;
  const int wr = wave >> 2, wc = wave & 3;
  const int m0 = by * BM, n0 = bx * BN;
  const int r16 = lane & 15, quad = lane >> 4;
  const int w16 = wave * 16;

  const int cg8 = (((lane & 3) ^ ((lane >> 2) & 3) ^ ((lane >> 4) & 3)) * 8);
  const f16* Ag = A + (long)(m0 + w16 + (lane >> 2)) * lda + cg8;
  const f16* Bg = B + (long)(n0 + w16 + (lane >> 2)) * ldb + cg8;

  const int NT = K / 64;

  STAGE_A(0, 0); STAGE_B(0, 0);
  STAGE_A(0, 1); STAGE_B(0, 1);
  STAGE_A(1, 0); STAGE_B(1, 0);

  f32x4 acc[RM][RN] = {};

  const int rc  = (quad ^ ((r16 ^ (r16 >> 2)) & 3)) * 8;
  const int rdA = (wr * WM + r16) * 32 + rc;
  const int rdB = (wc * WN + r16) * 32 + rc;

  if constexpr (RM == 8) { WAITVM(8); } else { WAITVM(6); }
  BAR();

  for (int t = 0; t < NT; ++t) {
    const int bp = t & 1;
    const f16* A0 = &Ash[bp][0][0];
    const f16* A1 = &Ash[bp][1][0];
    const f16* B0 = &Bsh[bp][0][0];
    const f16* B1 = &Bsh[bp][1][0];
    f16x8 af[4], bf[4];

    if constexpr (RM == 4) {
      // ---- phase 1: kk=0
#pragma unroll
      for (int i = 0; i < 4; i++) af[i] = *(const f16x8*)&A0[rdA + i * 512];
#pragma unroll
      for (int j = 0; j < 4; j++) bf[j] = *(const f16x8*)&B0[rdB + j * 512];
      if (t + 1 < NT) { STAGE_A(t + 1, 1); STAGE_B(t + 1, 1); }
      BAR();
      WAITLGKM0(); SB0();
      __builtin_amdgcn_s_setprio(1);
#pragma unroll
      for (int i = 0; i < 4; i++)
#pragma unroll
        for (int j = 0; j < 4; j++)
          acc[i][j] = __builtin_amdgcn_mfma_f32_16x16x32_f16(af[i], bf[j], acc[i][j], 0, 0, 0);
      __builtin_amdgcn_s_setprio(0); SB0();
      if (t < NT - 1) { WAITVM(6); } else { WAITVM(0); }
      BAR();
      // ---- phase 2: kk=1
#pragma unroll
      for (int i = 0; i < 4; i++) af[i] = *(const f16x8*)&A1[rdA + i * 512];
#pragma unroll
      for (int j = 0; j < 4; j++) bf[j] = *(const f16x8*)&B1[rdB + j * 512];
      if (t + 2 < NT) { STAGE_A(t + 2, 0); STAGE_B(t + 2, 0); }
      BAR();
      WAITLGKM0(); SB0();
      __builtin_amdgcn_s_setprio(1);
#pragma unroll
      for (int i = 0; i < 4; i++)
#pragma unroll
        for (int j = 0; j < 4; j++)
          acc[i][j] = __builtin_amdgcn_mfma_f32_16x16x32_f16(af[i], bf[j], acc[i][j], 0, 0, 0);
      __builtin_amdgcn_s_setprio(0); SB0();
      if (t < NT - 2) { WAITVM(6); } else if (t == NT - 2) { WAITVM(3); } else { WAITVM(0); }
      BAR();
    } else {
      // ---- phase 1: kk=0, rows 0-3
#pragma unroll
      for (int i = 0; i < 4; i++) af[i] = *(const f16x8*)&A0[rdA + i * 512];
#pragma unroll
      for (int j = 0; j < 4; j++) bf[j] = *(const f16x8*)&B0[rdB + j * 512];
      if (t + 1 < NT) STAGE_A(t + 1, 1);
      BAR();
      WAITLGKM0(); SB0();
      __builtin_amdgcn_s_setprio(1);
#pragma unroll
      for (int i = 0; i < 4; i++)
#pragma unroll
        for (int j = 0; j < 4; j++)
          acc[i][j] = __builtin_amdgcn_mfma_f32_16x16x32_f16(af[i], bf[j], acc[i][j], 0, 0, 0);
      __builtin_amdgcn_s_setprio(0); SB0();
      BAR();
      // ---- phase 2: kk=0, rows 4-7
#pragma unroll
      for (int i = 0; i < 4; i++) af[i] = *(const f16x8*)&A0[rdA + (4 + i) * 512];
      if (t + 1 < NT) STAGE_B(t + 1, 1);
      BAR();
      WAITLGKM0(); SB0();
      __builtin_amdgcn_s_setprio(1);
#pragma unroll
      for (int i = 0; i < 4; i++)
#pragma unroll
        for (int j = 0; j < 4; j++)
          acc[4 + i][j] = __builtin_amdgcn_mfma_f32_16x16x32_f16(af[i], bf[j], acc[4 + i][j], 0, 0, 0);
      __builtin_amdgcn_s_setprio(0); SB0();
      if (t < NT - 1) { WAITVM(6); } else { WAITVM(0); }
      BAR();
      // ---- phase 3: kk=1, rows 0-3
#pragma unroll
      for (int i = 0; i < 4; i++) af[i] = *(const f16x8*)&A1[rdA + i * 512];
#pragma unroll
      for (int j = 0; j < 4; j++) bf[j] = *(const f16x8*)&B1[rdB + j * 512];
      if (t + 2 < NT) STAGE_A(t + 2, 0);
      BAR();
      WAITLGKM0(); SB0();
      __builtin_amdgcn_s_setprio(1);
#pragma unroll
      for (int i = 0; i < 4; i++)
#pragma unroll
        for (int j = 0; j < 4; j++)
          acc[i][j] = __builtin_amdgcn_mfma_f32_16x16x32_f16(af[i], bf[j], acc[i][j], 0, 0, 0);
      __builtin_amdgcn_s_setprio(0); SB0();
      BAR();
      // ---- phase 4: kk=1, rows 4-7
#pragma unroll
      for (int i = 0; i < 4; i++) af[i] = *(const f16x8*)&A1[rdA + (4 + i) * 512];
      if (t + 2 < NT) STAGE_B(t + 2, 0);
      BAR();
      WAITLGKM0(); SB0();
      __builtin_amdgcn_s_setprio(1);
#pragma unroll
      for (int i = 0; i < 4; i++)
#pragma unroll
        for (int j = 0; j < 4; j++)
          acc[4 + i][j] = __builtin_amdgcn_mfma_f32_16x16x32_f16(af[i], bf[j], acc[4 + i][j], 0, 0, 0);
      __builtin_amdgcn_s_setprio(0); SB0();
      if (t < NT - 2) { WAITVM(6); } else if (t == NT - 2) { WAITVM(4); } else { WAITVM(0); }
      BAR();
    }
  }

  // epilogue. C/D layout (verified m89): col = lane&15, row = (lane>>4)*4 + reg
  float bias_j[RN];
#pragma unroll
  for (int j = 0; j < RN; j++) bias_j[j] = 0.f;
  if constexpr (BIAS) {
    const float* bias = (bz == 0) ? b0 : (bz == 1) ? b1 : b2;
#pragma unroll
    for (int j = 0; j < RN; j++) bias_j[j] = bias[n0 + wc * WN + j * 16 + r16];
  }
#pragma unroll
  for (int i = 0; i < RM; i++)
#pragma unroll
    for (int j = 0; j < RN; j++)
#pragma unroll
      for (int r = 0; r < 4; r++) {
        long row = m0 + wr * WM + i * 16 + quad * 4 + r;
        long col = n0 + wc * WN + j * 16 + r16;
        C[row * (long)ldc + col] = (OutT)(acc[i][j][r] + bias_j[j]);
      }
}

// ---------------------------------------------------------------------------
// One launch casts x (8.39M) + Wq/Wk/Wv (1.05M each) fp32 -> fp16.
__global__ __launch_bounds__(256) void cast_all(
    const float* __restrict__ x, const float* __restrict__ Wq,
    const float* __restrict__ Wk, const float* __restrict__ Wv,
    f16* __restrict__ Xh, f16* __restrict__ Wh)
{
  const long off = (long)blockIdx.x * 1024 + threadIdx.x * 4;
  const float* src;
  f16* dst;
  if (off < 8388608L) {
    src = x + off;
    dst = Xh + off;
  } else {
    const long o = off - 8388608L;
    src = (o < 1048576L) ? Wq + o
        : (o < 2097152L) ? Wk + (o - 1048576L)
                         : Wv + (o - 2097152L);
    dst = Wh + o;
  }
  const float4 v = *(const float4*)src;
  f16x4 h;
  h.x = (f16)v.x; h.y = (f16)v.y; h.z = (f16)v.z; h.w = (f16)v.w;
  *(f16x4*)dst = h;
}

// LayerNorm (gamma/beta; bias already folded into GEMM epilogue).
// One block per row, in-place fp16. grid (8192, 3)
__global__ __launch_bounds__(256) void ln_kernel(
    f16* __restrict__ P, const float* __restrict__ gamma,
    const float* __restrict__ beta)
{
  f16* p = P + (long)blockIdx.y * 8388608 + (long)blockIdx.x * 1024;
  const int tid = threadIdx.x;
  const int e = tid * 4;

  f16x4 raw = *(const f16x4*)(p + e);
  float v0 = (float)raw.x, v1 = (float)raw.y;
  float v2 = (float)raw.z, v3 = (float)raw.w;
  float s  = v0 + v1 + v2 + v3;
  float s2 = v0 * v0 + v1 * v1 + v2 * v2 + v3 * v3;

#pragma unroll
  for (int off = 32; off > 0; off >>= 1) {
    s  += __shfl_down(s, off, 64);
    s2 += __shfl_down(s2, off, 64);
  }
  __shared__ float red[10];
  const int wave = tid >> 6, lane = tid & 63;
  if (lane == 0) { red[wave] = s; red[4 + wave] = s2; }
  __syncthreads();
  if (tid == 0) {
    red[8] = red[0] + red[1] + red[2] + red[3];
    red[9] = red[4] + red[5] + red[6] + red[7];
  }
  __syncthreads();
  const float mu   = red[8] * (1.f / 1024.f);
  const float var  = red[9] * (1.f / 1024.f) - mu * mu;
  const float rstd = rsqrtf(var + 1e-5f);

  float4 gg = *(const float4*)(gamma + e);
  float4 be = *(const float4*)(beta + e);
  f16x4 o;
  o.x = (f16)((v0 - mu) * rstd * gg.x + be.x);
  o.y = (f16)((v1 - mu) * rstd * gg.y + be.y);
  o.z = (f16)((v2 - mu) * rstd * gg.z + be.z);
  o.w = (f16)((v3 - mu) * rstd * gg.w + be.w);
  *(f16x4*)(p + e) = o;
}

// V (S x D, fp16) -> Vt (D x S, fp16), per batch. grid (D/64, S/64, B)
__global__ __launch_bounds__(256) void transpose_kernel(const f16* __restrict__ V,
                                                        f16* __restrict__ Vt)
{
  const int S = 2048, D = 1024;
  const f16* v = V + (long)blockIdx.z * ((long)S * D);
  f16* vt = Vt + (long)blockIdx.z * ((long)D * S);
  __shared__ f16 tile[64][66];  // +2 pad -> conflict-free transposed reads
  const int d0 = blockIdx.x * 64, j0 = blockIdx.y * 64;
  const int tx = threadIdx.x & 63, ty = threadIdx.x >> 6;
#pragma unroll
  for (int r = ty; r < 64; r += 4)
    tile[r][tx] = v[(long)(j0 + r) * D + d0 + tx];
  __syncthreads();
#pragma unroll
  for (int r = ty; r < 64; r += 4)
    vt[(long)(d0 + r) * S + j0 + tx] = tile[tx][r];
}

// Row softmax over 2048 fp32 logits; writes fp16 probs in-place (first half of row).
__global__ __launch_bounds__(256) void softmax_kernel(float* __restrict__ Sc)
{
  float* srow = Sc + (long)blockIdx.x * 2048;
  const int tid = threadIdx.x;
  float4 a = ((const float4*)srow)[tid];
  float4 b = ((const float4*)srow)[256 + tid];

  float m = fmaxf(fmaxf(fmaxf(a.x, a.y), fmaxf(a.z, a.w)),
                  fmaxf(fmaxf(b.x, b.y), fmaxf(b.z, b.w)));
#pragma unroll
  for (int off = 32; off > 0; off >>= 1) m = fmaxf(m, __shfl_down(m, off, 64));
  __shared__ float red[6];
  const int wave = tid >> 6, lane = tid & 63;
  if (lane == 0) red[wave] = m;
  __syncthreads();
  if (tid == 0) red[4] = fmaxf(fmaxf(red[0], red[1]), fmaxf(red[2], red[3]));
  __syncthreads();
  const float M = red[4];

  a.x = __expf(a.x - M); a.y = __expf(a.y - M);
  a.z = __expf(a.z - M); a.w = __expf(a.w - M);
  b.x = __expf(b.x - M); b.y = __expf(b.y - M);
  b.z = __expf(b.z - M); b.w = __expf(b.w - M);
  float s = a.x + a.y + a.z + a.w + b.x + b.y + b.z + b.w;
#pragma unroll
  for (int off = 32; off > 0; off >>= 1) s += __shfl_down(s, off, 64);
  if (lane == 0) red[wave] = s;
  __syncthreads();
  if (tid == 0) red[5] = red[0] + red[1] + red[2] + red[3];
  __syncthreads();
  const float inv = 1.0f / red[5];

  f16* orow = (f16*)srow;  // safe: all reads happened before first barrier
  f16x4 oa, ob;
  oa.x = (f16)(a.x * inv); oa.y = (f16)(a.y * inv);
  oa.z = (f16)(a.z * inv); oa.w = (f16)(a.w * inv);
  ob.x = (f16)(b.x * inv); ob.y = (f16)(b.y * inv);
  ob.z = (f16)(b.z * inv); ob.w = (f16)(b.w * inv);
  ((f16x4*)orow)[tid]       = oa;
  ((f16x4*)orow)[256 + tid] = ob;
}

// ---------------------------------------------------------------------------
extern "C" void kernel_launch(void* const* d_in, const int* in_sizes, int n_in,
                              void* d_out, int out_size, void* d_ws, size_t ws_size,
                              hipStream_t stream)
{
  const float* x     = (const float*)d_in[0];
  const float* Wq    = (const float*)d_in[1];
  const float* bq    = (const float*)d_in[2];
  const float* Wk    = (const float*)d_in[3];
  const float* bk    = (const float*)d_in[4];
  const float* Wv    = (const float*)d_in[5];
  const float* bv    = (const float*)d_in[6];
  const float* gamma = (const float*)d_in[7];
  const float* beta  = (const float*)d_in[8];
  float* out = (float*)d_out;

  // ws layout:
  //  [0,48)MB   P  : Q,K,V fp16 slabs (8192x1024 each), LN in-place
  //  [48,64)MB  Vt : V transposed per batch (1024x2048 fp16)
  //  [64,..)    Sc : scores fp32 (4 x 2048x2048); softmax writes fp16 probs in-place
  //  Xh/Wh aliased inside the Sc region (dead before scores are written)
  char* ws = (char*)d_ws;
  f16*   P  = (f16*)(ws);
  f16*   Vt = (f16*)(ws + (48u << 20));
  float* Sc = (float*)(ws + (64u << 20));
  f16*   Xh = (f16*)(ws + (64u << 20));
  f16*   Wh = (f16*)(ws + (80u << 20));

  // 1. fp32 -> fp16 casts (single launch)
  cast_all<<<11264, 256, 0, stream>>>(x, Wq, Wk, Wv, Xh, Wh);

  // 2. projections + bias: P_h = Xh · Wh^T + b_h  (M=8192, N=1024, K=1024, z=h)
  //    r5 gemm_kn, 1536 blocks (6/CU)
  gemm_kn<f16, 0, true><<<1536, 256, 0, stream>>>(
      Xh, Wh, P, 1024, 1024, 1024, 1024, 0L, 1048576L, 8388608L,
      8, 64, bq, bk, bv);

  // 3. LayerNorm (gamma/beta), in-place fp16
  ln_kernel<<<dim3(8192, 3), 256, 0, stream>>>(P, gamma, beta);

  // 4. V -> Vt per batch
  transpose_kernel<<<dim3(16, 32, 4), 256, 0, stream>>>(P + 2L * 8388608, Vt);

  // 5. scores: Sc_b = Q_b · K_b^T  (M=N=2048, K=1024, z=batch, fp32 out)
  //    r3 gemm8p 256x256, 256 blocks (1/CU)
  gemm8p<256, 256, float, 1, false><<<256, 512, 0, stream>>>(
      P, P + 8388608, Sc, 1024, 1024, 2048, 1024, 2097152L, 2097152L, 4194304L,
      8, 8, nullptr, nullptr, nullptr);

  // 6. softmax rows (8192 rows), fp16 probs in-place (row pitch 4096 halves)
  softmax_kernel<<<8192, 256, 0, stream>>>(Sc);

  // 7. out_b = Pr_b · Vt_b^T  (M=2048, N=1024, K=2048, z=batch, fp32 out)
  //    r3 gemm8p 128x256, 256 blocks (1/CU)
  gemm8p<128, 256, float, 1, false><<<256, 512, 0, stream>>>(
      (const f16*)Sc, Vt, out, 4096, 2048, 1024, 2048, 8388608L, 2097152L, 2097152L,
      4, 16, nullptr, nullptr, nullptr);
}

// Round 9
// 292.836 us; speedup vs baseline: 1.1619x; 1.0269x over previous
//
#include <hip/hip_runtime.h>

typedef _Float16 f16;
typedef __attribute__((ext_vector_type(4))) _Float16 f16x4;
typedef __attribute__((ext_vector_type(8))) _Float16 f16x8;
typedef __attribute__((ext_vector_type(4))) float f32x4;

#define GLB_AS __attribute__((address_space(1)))
#define LDS_AS __attribute__((address_space(3)))

__device__ __forceinline__ void async_copy16(const void* g, void* l) {
  // 16B-per-lane global->LDS DMA; LDS dest = wave-uniform base + lane*16
  __builtin_amdgcn_global_load_lds((const GLB_AS void*)g, (LDS_AS void*)l, 16, 0, 0);
}

#define WAITVM(N) asm volatile("s_waitcnt vmcnt(" #N ")" ::: "memory")
#define WAITLGKM0() asm volatile("s_waitcnt lgkmcnt(0)" ::: "memory")
#define BAR() __builtin_amdgcn_s_barrier()
#define SB0() __builtin_amdgcn_sched_barrier(0)

// ===========================================================================
// PROJECTION GEMM — r5 verbatim (best-measured: 72.8 us, VGPR 56, 0 conflicts)
// ===========================================================================
template <typename OutT, int MODE, bool BIAS>
__global__ __launch_bounds__(256, 4) void gemm_kn(
    const f16* __restrict__ A, const f16* __restrict__ B, OutT* __restrict__ C,
    int lda, int ldb, int ldc, int K, long sA, long sB, long sC,
    int tiles_x, int tiles_y,
    const float* __restrict__ b0, const float* __restrict__ b1,
    const float* __restrict__ b2)
{
  constexpr int BM = 128, BK = 32;
  __shared__ __align__(16) f16 Ash[2][BM * BK];
  __shared__ __align__(16) f16 Bsh[2][BM * BK];

  int bx, by, bz;
  {
    const int n = blockIdx.x;
    if (MODE == 0) {
      by = n % tiles_y;
      const int r = n / tiles_y;
      bx = r % tiles_x;
      bz = r / tiles_x;
    } else {
      const int j = n & 7, i = n >> 3;
      bz = j >> 1;
      bx = i >> 3;
      by = (j & 1) * 8 + (i & 7);
    }
  }

  A += (long)bz * sA;
  B += (long)bz * sB;
  C += (long)bz * sC;

  const int tid  = threadIdx.x;
  const int wave = tid >> 6, lane = tid & 63;
  const int m0 = by * BM, n0 = bx * BM;
  const int wm = (wave >> 1) * 64, wn = (wave & 1) * 64;
  const int r16 = lane & 15, quad = lane >> 4;

  const int srow = wave * 32 + (lane >> 2);
  const int skb  = ((lane & 3) ^ ((lane >> 3) & 3)) * 8;
  const f16* Ag = A + (long)(m0 + srow) * lda + skb;
  const f16* Bg = B + (long)(n0 + srow) * ldb + skb;
  const int lo0 = (wave * 32) * BK;
  const int lo1 = (wave * 32 + 16) * BK;

  async_copy16(Ag,                  &Ash[0][lo0]);
  async_copy16(Ag + 16 * (long)lda, &Ash[0][lo1]);
  async_copy16(Bg,                  &Bsh[0][lo0]);
  async_copy16(Bg + 16 * (long)ldb, &Bsh[0][lo1]);

  f32x4 acc[4][4] = {};

  const int cchunk = (quad ^ ((r16 >> 1) & 3)) * 8;

  int buf = 0;
  for (int k0 = 0; k0 < K; k0 += BK, buf ^= 1) {
    __syncthreads();

    if (k0 + BK < K) {
      const int nb = buf ^ 1;
      const long k1 = k0 + BK;
      async_copy16(Ag + k1,                  &Ash[nb][lo0]);
      async_copy16(Ag + k1 + 16 * (long)lda, &Ash[nb][lo1]);
      async_copy16(Bg + k1,                  &Bsh[nb][lo0]);
      async_copy16(Bg + k1 + 16 * (long)ldb, &Bsh[nb][lo1]);
    }

    f16x8 bf[4];
#pragma unroll
    for (int j = 0; j < 4; j++)
      bf[j] = *(const f16x8*)&Bsh[buf][(wn + j * 16 + r16) * BK + cchunk];
#pragma unroll
    for (int i = 0; i < 4; i++) {
      f16x8 af = *(const f16x8*)&Ash[buf][(wm + i * 16 + r16) * BK + cchunk];
#pragma unroll
      for (int j = 0; j < 4; j++)
        acc[i][j] = __builtin_amdgcn_mfma_f32_16x16x32_f16(af, bf[j], acc[i][j], 0, 0, 0);
    }
  }

  float bias_j[4] = {0.f, 0.f, 0.f, 0.f};
  if (BIAS) {
    const float* bias = (bz == 0) ? b0 : (bz == 1) ? b1 : b2;
#pragma unroll
    for (int j = 0; j < 4; j++) bias_j[j] = bias[n0 + wn + j * 16 + r16];
  }
#pragma unroll
  for (int i = 0; i < 4; i++)
#pragma unroll
    for (int j = 0; j < 4; j++)
#pragma unroll
      for (int r = 0; r < 4; r++) {
        long row = m0 + wm + i * 16 + quad * 4 + r;
        long col = n0 + wn + j * 16 + r16;
        C[row * (long)ldc + col] = (OutT)(acc[i][j][r] + bias_j[j]);
      }
}

// ===========================================================================
// ATTENTION GEMMs — r3 K-loop verbatim; epilogue extensions:
//  EPI==1 (scores): per-row/per-col-tile softmax stats (m, l=sum exp(s-m)),
//    write P~ = exp(s-m) as fp16 + (m,l) to statsB. Math: flash 2-pass.
//    Reduction: in-thread over j -> shfl_xor over r16 (cols) -> LDS over wc.
//  ALPHA (PV): scale A-fragments by alpha[bz][T][row] (T = score col-tile).
//    A-operand layout row = r16 -> one scalar per lane per fragment.
//    In-loop alpha loads are SAFE for counted vmcnt: extra queue entries make
//    fixed-N waits strictly MORE conservative (older stages complete earlier).
// ===========================================================================
#define STAGE_A(t_, kk_) do {                                                \
    const long _k = (long)(t_) * 64 + (kk_) * 32;                            \
    f16* _d = &Ash[(t_) & 1][kk_][w16 * 32];                                 \
    async_copy16(Ag + _k, _d);                                               \
    if constexpr (IA == 2) async_copy16(Ag + _k + 128l * lda, _d + 4096);    \
  } while (0)
#define STAGE_B(t_, kk_) do {                                                \
    const long _k = (long)(t_) * 64 + (kk_) * 32;                            \
    f16* _d = &Bsh[(t_) & 1][kk_][w16 * 32];                                 \
    async_copy16(Bg + _k, _d);                                               \
    async_copy16(Bg + _k + 128l * ldb, _d + 4096);                           \
  } while (0)

template <int BM, int BN, typename OutT, int MODE, bool BIAS, int EPI, bool ALPHA>
__global__ __launch_bounds__(512, 2) void gemm8p(
    const f16* __restrict__ A, const f16* __restrict__ B, OutT* __restrict__ C,
    int lda, int ldb, int ldc, int K, long sA, long sB, long sC,
    int tiles_x, int tiles_y,
    const float* __restrict__ b0, const float* __restrict__ b1,
    const float* __restrict__ b2,
    float2* __restrict__ statsB, const float* __restrict__ alphaB)
{
  constexpr int WM = BM / 2, WN = BN / 4;
  constexpr int RM = WM / 16, RN = WN / 16;
  constexpr int IA = BM / 128;
  static_assert(RN == 4 && BN == 256, "template assumes BN=256");

  __shared__ __align__(16) f16 Ash[2][2][BM * 32];
  __shared__ __align__(16) f16 Bsh[2][2][BN * 32];

  int bx, by, bz;
  {
    const int n = blockIdx.x;
    if (MODE == 0) {
      by = n % tiles_y;
      const int r = n / tiles_y;
      bx = r % tiles_x;
      bz = r / tiles_x;
    } else {
      const int j = n & 7, i = n >> 3, th = tiles_y >> 1;
      bz = j >> 1;
      bx = i / th;
      by = (j & 1) * th + i % th;
    }
  }

  A += (long)bz * sA;
  B += (long)bz * sB;
  C += (long)bz * sC;

  const int tid  = threadIdx.x;
  const int wave = tid >> 6, lane = tid & 63;
  const int wr = wave >> 2, wc = wave & 3;
  const int m0 = by * BM, n0 = bx * BN;
  const int r16 = lane & 15, quad = lane >> 4;
  const int w16 = wave * 16;

  const int cg8 = (((lane & 3) ^ ((lane >> 2) & 3) ^ ((lane >> 4) & 3)) * 8);
  const f16* Ag = A + (long)(m0 + w16 + (lane >> 2)) * lda + cg8;
  const f16* Bg = B + (long)(n0 + w16 + (lane >> 2)) * ldb + cg8;

  const int NT = K / 64;

  STAGE_A(0, 0); STAGE_B(0, 0);
  STAGE_A(0, 1); STAGE_B(0, 1);
  STAGE_A(1, 0); STAGE_B(1, 0);

  f32x4 acc[RM][RN] = {};

  const int rc  = (quad ^ ((r16 ^ (r16 >> 2)) & 3)) * 8;
  const int rdA = (wr * WM + r16) * 32 + rc;
  const int rdB = (wc * WN + r16) * 32 + rc;

  // ALPHA: per-fragment-row scale, reloaded when the score col-tile T changes
  f16 ah[RM == 4 ? 4 : 1];
  const float* aBase = nullptr;
  if constexpr (ALPHA) aBase = alphaB + (long)bz * 8 * 2048 + m0 + wr * WM + r16;

  if constexpr (RM == 8) { WAITVM(8); } else { WAITVM(6); }
  BAR();

  for (int t = 0; t < NT; ++t) {
    if constexpr (ALPHA) {
      if ((t & 3) == 0) {
        const int T = t >> 2;
#pragma unroll
        for (int i = 0; i < 4; i++)
          ah[i] = (f16)aBase[(long)T * 2048 + i * 16];
      }
    }
    const int bp = t & 1;
    const f16* A0 = &Ash[bp][0][0];
    const f16* A1 = &Ash[bp][1][0];
    const f16* B0 = &Bsh[bp][0][0];
    const f16* B1 = &Bsh[bp][1][0];
    f16x8 af[4], bf[4];

    if constexpr (RM == 4) {
      // ---- phase 1: kk=0
#pragma unroll
      for (int i = 0; i < 4; i++) {
        af[i] = *(const f16x8*)&A0[rdA + i * 512];
        if constexpr (ALPHA) af[i] = af[i] * ah[i];
      }
#pragma unroll
      for (int j = 0; j < 4; j++) bf[j] = *(const f16x8*)&B0[rdB + j * 512];
      if (t + 1 < NT) { STAGE_A(t + 1, 1); STAGE_B(t + 1, 1); }
      BAR();
      WAITLGKM0(); SB0();
      __builtin_amdgcn_s_setprio(1);
#pragma unroll
      for (int i = 0; i < 4; i++)
#pragma unroll
        for (int j = 0; j < 4; j++)
          acc[i][j] = __builtin_amdgcn_mfma_f32_16x16x32_f16(af[i], bf[j], acc[i][j], 0, 0, 0);
      __builtin_amdgcn_s_setprio(0); SB0();
      if (t < NT - 1) { WAITVM(6); } else { WAITVM(0); }
      BAR();
      // ---- phase 2: kk=1
#pragma unroll
      for (int i = 0; i < 4; i++) {
        af[i] = *(const f16x8*)&A1[rdA + i * 512];
        if constexpr (ALPHA) af[i] = af[i] * ah[i];
      }
#pragma unroll
      for (int j = 0; j < 4; j++) bf[j] = *(const f16x8*)&B1[rdB + j * 512];
      if (t + 2 < NT) { STAGE_A(t + 2, 0); STAGE_B(t + 2, 0); }
      BAR();
      WAITLGKM0(); SB0();
      __builtin_amdgcn_s_setprio(1);
#pragma unroll
      for (int i = 0; i < 4; i++)
#pragma unroll
        for (int j = 0; j < 4; j++)
          acc[i][j] = __builtin_amdgcn_mfma_f32_16x16x32_f16(af[i], bf[j], acc[i][j], 0, 0, 0);
      __builtin_amdgcn_s_setprio(0); SB0();
      if (t < NT - 2) { WAITVM(6); } else if (t == NT - 2) { WAITVM(3); } else { WAITVM(0); }
      BAR();
    } else {
      // ---- phase 1: kk=0, rows 0-3
#pragma unroll
      for (int i = 0; i < 4; i++) af[i] = *(const f16x8*)&A0[rdA + i * 512];
#pragma unroll
      for (int j = 0; j < 4; j++) bf[j] = *(const f16x8*)&B0[rdB + j * 512];
      if (t + 1 < NT) STAGE_A(t + 1, 1);
      BAR();
      WAITLGKM0(); SB0();
      __builtin_amdgcn_s_setprio(1);
#pragma unroll
      for (int i = 0; i < 4; i++)
#pragma unroll
        for (int j = 0; j < 4; j++)
          acc[i][j] = __builtin_amdgcn_mfma_f32_16x16x32_f16(af[i], bf[j], acc[i][j], 0, 0, 0);
      __builtin_amdgcn_s_setprio(0); SB0();
      BAR();
      // ---- phase 2: kk=0, rows 4-7
#pragma unroll
      for (int i = 0; i < 4; i++) af[i] = *(const f16x8*)&A0[rdA + (4 + i) * 512];
      if (t + 1 < NT) STAGE_B(t + 1, 1);
      BAR();
      WAITLGKM0(); SB0();
      __builtin_amdgcn_s_setprio(1);
#pragma unroll
      for (int i = 0; i < 4; i++)
#pragma unroll
        for (int j = 0; j < 4; j++)
          acc[4 + i][j] = __builtin_amdgcn_mfma_f32_16x16x32_f16(af[i], bf[j], acc[4 + i][j], 0, 0, 0);
      __builtin_amdgcn_s_setprio(0); SB0();
      if (t < NT - 1) { WAITVM(6); } else { WAITVM(0); }
      BAR();
      // ---- phase 3: kk=1, rows 0-3
#pragma unroll
      for (int i = 0; i < 4; i++) af[i] = *(const f16x8*)&A1[rdA + i * 512];
#pragma unroll
      for (int j = 0; j < 4; j++) bf[j] = *(const f16x8*)&B1[rdB + j * 512];
      if (t + 2 < NT) STAGE_A(t + 2, 0);
      BAR();
      WAITLGKM0(); SB0();
      __builtin_amdgcn_s_setprio(1);
#pragma unroll
      for (int i = 0; i < 4; i++)
#pragma unroll
        for (int j = 0; j < 4; j++)
          acc[i][j] = __builtin_amdgcn_mfma_f32_16x16x32_f16(af[i], bf[j], acc[i][j], 0, 0, 0);
      __builtin_amdgcn_s_setprio(0); SB0();
      BAR();
      // ---- phase 4: kk=1, rows 4-7
#pragma unroll
      for (int i = 0; i < 4; i++) af[i] = *(const f16x8*)&A1[rdA + (4 + i) * 512];
      if (t + 2 < NT) STAGE_B(t + 2, 0);
      BAR();
      WAITLGKM0(); SB0();
      __builtin_amdgcn_s_setprio(1);
#pragma unroll
      for (int i = 0; i < 4; i++)
#pragma unroll
        for (int j = 0; j < 4; j++)
          acc[4 + i][j] = __builtin_amdgcn_mfma_f32_16x16x32_f16(af[i], bf[j], acc[4 + i][j], 0, 0, 0);
      __builtin_amdgcn_s_setprio(0); SB0();
      if (t < NT - 2) { WAITVM(6); } else if (t == NT - 2) { WAITVM(4); } else { WAITVM(0); }
      BAR();
    }
  }

  // ---- EPI==1: per-row softmax stats over this block's BN cols, exp in place
  if constexpr (EPI == 1) {
    // LDS scratch over dead Ash: red[256][4] + fin[256]
    float* red = (float*)&Ash[0][0][0];
    float* fin = red + 1024;

    // row R = wr*128 + i*16 + quad*4 + r ; cols per thread: wc*64 + j*16 + r16
    float mloc[RM][4];
#pragma unroll
    for (int i = 0; i < RM; i++)
#pragma unroll
      for (int r = 0; r < 4; r++) {
        float m = fmaxf(fmaxf(acc[i][0][r], acc[i][1][r]),
                        fmaxf(acc[i][2][r], acc[i][3][r]));
#pragma unroll
        for (int msk = 1; msk <= 8; msk <<= 1) m = fmaxf(m, __shfl_xor(m, msk, 64));
        mloc[i][r] = m;
      }
    if (r16 == 0) {
#pragma unroll
      for (int i = 0; i < RM; i++)
#pragma unroll
        for (int r = 0; r < 4; r++)
          red[(wr * 128 + i * 16 + quad * 4 + r) * 4 + wc] = mloc[i][r];
    }
    __syncthreads();
    if (tid < 256)
      fin[tid] = fmaxf(fmaxf(red[tid * 4], red[tid * 4 + 1]),
                       fmaxf(red[tid * 4 + 2], red[tid * 4 + 3]));
    __syncthreads();
#pragma unroll
    for (int i = 0; i < RM; i++)
#pragma unroll
      for (int r = 0; r < 4; r++) {
        const float m = fin[wr * 128 + i * 16 + quad * 4 + r];
        float s = 0.f;
#pragma unroll
        for (int j = 0; j < 4; j++) {
          acc[i][j][r] = __expf(acc[i][j][r] - m);
          s += acc[i][j][r];
        }
#pragma unroll
        for (int msk = 1; msk <= 8; msk <<= 1) s += __shfl_xor(s, msk, 64);
        mloc[i][r] = s;  // reuse as sum
      }
    if (r16 == 0) {
#pragma unroll
      for (int i = 0; i < RM; i++)
#pragma unroll
        for (int r = 0; r < 4; r++)
          red[(wr * 128 + i * 16 + quad * 4 + r) * 4 + wc] = mloc[i][r];
    }
    __syncthreads();
    if (tid < 256) {
      const float L = red[tid * 4] + red[tid * 4 + 1] + red[tid * 4 + 2] + red[tid * 4 + 3];
      statsB[((long)bz * 8 + bx) * 2048 + m0 + tid] = make_float2(fin[tid], L);
    }
  }

  float bias_j[RN];
#pragma unroll
  for (int j = 0; j < RN; j++) bias_j[j] = 0.f;
  if constexpr (BIAS) {
    const float* bias = (bz == 0) ? b0 : (bz == 1) ? b1 : b2;
#pragma unroll
    for (int j = 0; j < RN; j++) bias_j[j] = bias[n0 + wc * WN + j * 16 + r16];
  }
#pragma unroll
  for (int i = 0; i < RM; i++)
#pragma unroll
    for (int j = 0; j < RN; j++)
#pragma unroll
      for (int r = 0; r < 4; r++) {
        long row = m0 + wr * WM + i * 16 + quad * 4 + r;
        long col = n0 + wc * WN + j * 16 + r16;
        C[row * (long)ldc + col] = (OutT)(acc[i][j][r] + bias_j[j]);
      }
}

// Combine per-tile stats: M = max m_t, L = sum l_t exp(m_t-M),
// alpha[bz][t][row] = exp(m_t-M)/L. One thread per row. grid 32x256.
__global__ __launch_bounds__(256) void reduce_stats(
    const float2* __restrict__ st, float* __restrict__ al)
{
  const int r = blockIdx.x * 256 + threadIdx.x;  // 0..8191
  const int bz = r >> 11, row = r & 2047;
  float m[8], l[8];
#pragma unroll
  for (int t = 0; t < 8; t++) {
    const float2 v = st[((long)bz * 8 + t) * 2048 + row];
    m[t] = v.x; l[t] = v.y;
  }
  float M = m[0];
#pragma unroll
  for (int t = 1; t < 8; t++) M = fmaxf(M, m[t]);
  float L = 0.f;
#pragma unroll
  for (int t = 0; t < 8; t++) L += l[t] * __expf(m[t] - M);
  const float inv = 1.0f / L;
#pragma unroll
  for (int t = 0; t < 8; t++)
    al[((long)bz * 8 + t) * 2048 + row] = __expf(m[t] - M) * inv;
}

// ---------------------------------------------------------------------------
__global__ __launch_bounds__(256) void cast_all(
    const float* __restrict__ x, const float* __restrict__ Wq,
    const float* __restrict__ Wk, const float* __restrict__ Wv,
    f16* __restrict__ Xh, f16* __restrict__ Wh)
{
  const long off = (long)blockIdx.x * 1024 + threadIdx.x * 4;
  const float* src;
  f16* dst;
  if (off < 8388608L) {
    src = x + off;
    dst = Xh + off;
  } else {
    const long o = off - 8388608L;
    src = (o < 1048576L) ? Wq + o
        : (o < 2097152L) ? Wk + (o - 1048576L)
                         : Wv + (o - 2097152L);
    dst = Wh + o;
  }
  const float4 v = *(const float4*)src;
  f16x4 h;
  h.x = (f16)v.x; h.y = (f16)v.y; h.z = (f16)v.z; h.w = (f16)v.w;
  *(f16x4*)dst = h;
}

__global__ __launch_bounds__(256) void ln_kernel(
    f16* __restrict__ P, const float* __restrict__ gamma,
    const float* __restrict__ beta)
{
  f16* p = P + (long)blockIdx.y * 8388608 + (long)blockIdx.x * 1024;
  const int tid = threadIdx.x;
  const int e = tid * 4;

  f16x4 raw = *(const f16x4*)(p + e);
  float v0 = (float)raw.x, v1 = (float)raw.y;
  float v2 = (float)raw.z, v3 = (float)raw.w;
  float s  = v0 + v1 + v2 + v3;
  float s2 = v0 * v0 + v1 * v1 + v2 * v2 + v3 * v3;

#pragma unroll
  for (int off = 32; off > 0; off >>= 1) {
    s  += __shfl_down(s, off, 64);
    s2 += __shfl_down(s2, off, 64);
  }
  __shared__ float red[10];
  const int wave = tid >> 6, lane = tid & 63;
  if (lane == 0) { red[wave] = s; red[4 + wave] = s2; }
  __syncthreads();
  if (tid == 0) {
    red[8] = red[0] + red[1] + red[2] + red[3];
    red[9] = red[4] + red[5] + red[6] + red[7];
  }
  __syncthreads();
  const float mu   = red[8] * (1.f / 1024.f);
  const float var  = red[9] * (1.f / 1024.f) - mu * mu;
  const float rstd = rsqrtf(var + 1e-5f);

  float4 gg = *(const float4*)(gamma + e);
  float4 be = *(const float4*)(beta + e);
  f16x4 o;
  o.x = (f16)((v0 - mu) * rstd * gg.x + be.x);
  o.y = (f16)((v1 - mu) * rstd * gg.y + be.y);
  o.z = (f16)((v2 - mu) * rstd * gg.z + be.z);
  o.w = (f16)((v3 - mu) * rstd * gg.w + be.w);
  *(f16x4*)(p + e) = o;
}

__global__ __launch_bounds__(256) void transpose_kernel(const f16* __restrict__ V,
                                                        f16* __restrict__ Vt)
{
  const int S = 2048, D = 1024;
  const f16* v = V + (long)blockIdx.z * ((long)S * D);
  f16* vt = Vt + (long)blockIdx.z * ((long)D * S);
  __shared__ f16 tile[64][66];
  const int d0 = blockIdx.x * 64, j0 = blockIdx.y * 64;
  const int tx = threadIdx.x & 63, ty = threadIdx.x >> 6;
#pragma unroll
  for (int r = ty; r < 64; r += 4)
    tile[r][tx] = v[(long)(j0 + r) * D + d0 + tx];
  __syncthreads();
#pragma unroll
  for (int r = ty; r < 64; r += 4)
    vt[(long)(d0 + r) * S + j0 + tx] = tile[tx][r];
}

// ---------------------------------------------------------------------------
extern "C" void kernel_launch(void* const* d_in, const int* in_sizes, int n_in,
                              void* d_out, int out_size, void* d_ws, size_t ws_size,
                              hipStream_t stream)
{
  const float* x     = (const float*)d_in[0];
  const float* Wq    = (const float*)d_in[1];
  const float* bq    = (const float*)d_in[2];
  const float* Wk    = (const float*)d_in[3];
  const float* bk    = (const float*)d_in[4];
  const float* Wv    = (const float*)d_in[5];
  const float* bv    = (const float*)d_in[6];
  const float* gamma = (const float*)d_in[7];
  const float* beta  = (const float*)d_in[8];
  float* out = (float*)d_out;

  // ws layout (<= 98 MB):
  //  [0,48)MB    P     : Q,K,V fp16 slabs (8192x1024 each), LN in-place
  //  [48,64)MB   Vt    : V transposed per batch (1024x2048 fp16)
  //  [64,96)MB   Pr    : P~ = exp(s-m) fp16, 4 x 2048x2048 (pitch 2048)
  //  [96,96.5)   stats : (m,l) float2 [bz][tile][row]  (4x8x2048)
  //  [96.5,97)   alpha : float [bz][tile][row]
  //  Xh/Wh alias [64,86) (dead before Pr is written)
  char* ws = (char*)d_ws;
  f16*    P     = (f16*)(ws);
  f16*    Vt    = (f16*)(ws + (48u << 20));
  f16*    Pr    = (f16*)(ws + (64u << 20));
  f16*    Xh    = (f16*)(ws + (64u << 20));
  f16*    Wh    = (f16*)(ws + (80u << 20));
  float2* stats = (float2*)(ws + (96u << 20));
  float*  alpha = (float*)(ws + (96u << 20) + (512u << 10));

  // 1. fp32 -> fp16 casts
  cast_all<<<11264, 256, 0, stream>>>(x, Wq, Wk, Wv, Xh, Wh);

  // 2. projections + bias (M=8192, N=1024, K=1024, z=head)
  gemm_kn<f16, 0, true><<<1536, 256, 0, stream>>>(
      Xh, Wh, P, 1024, 1024, 1024, 1024, 0L, 1048576L, 8388608L,
      8, 64, bq, bk, bv);

  // 3. LayerNorm in-place
  ln_kernel<<<dim3(8192, 3), 256, 0, stream>>>(P, gamma, beta);

  // 4. V -> Vt
  transpose_kernel<<<dim3(16, 32, 4), 256, 0, stream>>>(P + 2L * 8388608, Vt);

  // 5. scores + per-tile softmax stats: Pr = exp(QK^T - m_tile) fp16
  gemm8p<256, 256, f16, 1, false, 1, false><<<256, 512, 0, stream>>>(
      P, P + 8388608, Pr, 1024, 1024, 2048, 1024, 2097152L, 2097152L, 4194304L,
      8, 8, nullptr, nullptr, nullptr, stats, nullptr);

  // 6. combine stats -> alpha (tiny)
  reduce_stats<<<32, 256, 0, stream>>>(stats, alpha);

  // 7. out = sum_T alpha_T * (Pr_T · Vt_T)  (M=2048, N=1024, K=2048, z=batch)
  gemm8p<128, 256, float, 1, false, 0, true><<<256, 512, 0, stream>>>(
      Pr, Vt, out, 2048, 2048, 1024, 2048, 4194304L, 2097152L, 2097152L,
      4, 16, nullptr, nullptr, nullptr, nullptr, alpha);
}